// Round 11
// baseline (6030.238 us; speedup 1.0000x reference)
//
#include <hip/hip_runtime.h>

#define T_STEPS 2048
#define BATCH   256
#define ISZ     512
#define HSZ     512
#define GSZ     2048   // 4*H
#define KSZ     1024   // I + H
#define XH      1024   // LDS row stride bytes (512 bf16, swizzled, no pad)

// XOR swizzle (bits 4-6 of byte col XOR row&7) — validated in R10.
#define SWZ(row, col) ((col) ^ (((row) & 7) << 4))

using bf16x8 = __attribute__((ext_vector_type(8))) __bf16;
using f32x4  = __attribute__((ext_vector_type(4))) float;
using i32x4  = __attribute__((ext_vector_type(4))) int;

// lgkm-only barrier: all cross-wave edges are LDS (lgkm-drained); VMEM edges are
// handled by the tagged protocol's fused vmcnt(0) + explicit register liveness.
#define BARL() asm volatile("s_waitcnt lgkmcnt(0)\n\ts_barrier" ::: "memory")

// ---------------- workspace layout (bytes) ----------------
// 0        : W_cat  bf16 [2048][1024]        (4 MB)
// 4194304  : bias   f32  [2048]              (8 KB)
// 4202496  : thbuf0 u64  [256 rows][256]     (512 KB)  {2xbf16 h | u32 tag}
// 4726784  : thbuf1 u64  [256 rows][256]     (512 KB)

__device__ __forceinline__ unsigned short f2bf(float f) {
    unsigned int u = __float_as_uint(f);
    unsigned int r = (u + 0x7FFFu + ((u >> 16) & 1u)) >> 16;
    return (unsigned short)r;
}
__device__ __forceinline__ float bf2f(unsigned int bits16) {
    return __uint_as_float(bits16 << 16);
}
__device__ __forceinline__ float sigf(float x)   { return 1.0f / (1.0f + __expf(-x)); }
__device__ __forceinline__ float tanh_f(float x) { return 2.0f / (1.0f + __expf(-2.0f * x)) - 1.0f; }

// ---------------- pack W_ih|W_hh -> bf16 W_cat ----------------
__global__ void pack_weights(const float* __restrict__ Wih,
                             const float* __restrict__ Whh,
                             unsigned short* __restrict__ Wcat) {
    int gid = blockIdx.x * blockDim.x + threadIdx.x;   // 0 .. 524287
    int n   = gid >> 8;
    int k4  = (gid & 255) * 4;
    const float* src = (k4 < ISZ) ? (Wih + (size_t)n * ISZ + k4)
                                  : (Whh + (size_t)n * HSZ + (k4 - ISZ));
    float4 v = *(const float4*)src;
    ushort4 o;
    o.x = f2bf(v.x); o.y = f2bf(v.y); o.z = f2bf(v.z); o.w = f2bf(v.w);
    *(ushort4*)(Wcat + (size_t)n * KSZ + k4) = o;
}

// ---------------- init: tagged h buffers = 0, bias = b_ih + b_hh ----------------
__global__ void init_state(unsigned int* __restrict__ thbufs,   // both buffers, 262144 u32
                           float* __restrict__ bias,
                           const float* __restrict__ b_ih, const float* __restrict__ b_hh) {
    int gid = blockIdx.x * blockDim.x + threadIdx.x;
    if (gid < 262144) thbufs[gid] = 0u;
    if (gid < GSZ)    bias[gid] = b_ih[gid] + b_hh[gid];
}

// ---------------- persistent LSTM: wave-specialized split-K pipeline ----------------
// 256 WGs x 512 thr (8 waves, 2/SIMD). group g = bid&15 owns batch rows [g*16,+16);
// WG wgi = bid>>4 owns hidden cols [wgi*32,+32). Waves 0-3 (x-waves): gate w,
// K [0,512) x-contribution + out-dot. Waves 4-7 (h-waves): gate w-4, K [512,1024)
// h-contribution + pointwise + publish + probe.
//
// R11 changes vs R10:
// (1) wf pinned with "+a" -> AGPR side of the unified file (128 AGPR + ~120 arch
//     VGPR = 248/wave, 2 waves/SIMD). R10's "+v" pin spilled to scratch (VGPR=120
//     unchanged), leaving weight re-reads at ~26 TB/s ~ 75% of the L2 ceiling.
//     gfx950 MFMA reads A/B from AGPR directly -> no copies.
// (2) pointwise+publish on h-waves only; publish has NO internal wait -- the next
//     probe's fused vmcnt(0) is the drain. pubword stays LIVE across the iteration
//     (dummy use after the probe) so its register cannot be reused while the store
//     is in flight (the actual R7/R8 bug, fixed structurally).
// (3) all barriers lgkm-only: every cross-wave edge is LDS; x prefetch and the
//     out store stay in flight across barriers.
__global__ __launch_bounds__(512, 2) void lstm_persist(
    const float* __restrict__ x,
    const unsigned short* __restrict__ Wcat,
    const float* __restrict__ bias,
    const float* __restrict__ Wout,
    const float* __restrict__ bout,
    unsigned long long* thbuf0,
    unsigned long long* thbuf1,
    float* __restrict__ out)
{
    __shared__ __align__(16) char xlds0[16 * XH];   // x_t  bf16, double-buffered
    __shared__ __align__(16) char xlds1[16 * XH];
    __shared__ __align__(16) char hlds [16 * XH];   // h_{t-1} bf16
    __shared__ float gbuf[4][16][35];               // combined gates (padded rows)
    __shared__ float obuf[4];                       // out-dot wave partials

    const int tid  = threadIdx.x;
    const int lane = tid & 63;
    const int w    = tid >> 6;           // 0..7
    const int gate = w & 3;
    const bool isx = (w < 4);
    const int g    = blockIdx.x & 15;
    const int wgi  = blockIdx.x >> 4;
    const int r0   = lane & 15;
    const int hi   = lane >> 4;          // 0..3

    // ---- W fragments: 16 k-iters x 2 col-frags, pinned into AGPRs ----
    const int kb = isx ? 0 : 16;         // k-iter base (x half / h half)
    const int n0 = gate * HSZ + wgi * 32 + r0;
    const int n1 = n0 + 16;
    bf16x8 wf0[16], wf1[16];
    #pragma unroll
    for (int it = 0; it < 16; ++it) {
        wf0[it] = *(const bf16x8*)(Wcat + (size_t)n0 * KSZ + (kb + it) * 32 + hi * 8);
        wf1[it] = *(const bf16x8*)(Wcat + (size_t)n1 * KSZ + (kb + it) * 32 + hi * 8);
    }
    #pragma unroll
    for (int it = 0; it < 16; ++it) {
        asm volatile("" : "+a"(wf0[it]));   // AGPR residency: no remat, no scratch
        asm volatile("" : "+a"(wf1[it]));
    }
    const float bv0 = bias[n0];
    const float bv1 = bias[n1];
    const float bo  = bout[0];

    // ---- h-wave pointwise mapping: thread ht -> (row ht>>4, cols (ht&15)*2+{0,1}) ----
    const int ht  = tid & 255;           // h-waves: 0..255
    const int pr2 = ht >> 4;             // 0..15
    const int cl  = (ht & 15) * 2;       // 0..30
    float cst0 = 0.f, cst1 = 0.f;        // cell state (h-waves), all 2048 steps

    // ---- out-dot weights (x-wave threads: cols 2*tid, 2*tid+1) ----
    float woA = 0.f, woB = 0.f;
    if (isx) { woA = Wout[tid * 2]; woB = Wout[tid * 2 + 1]; }

    // ---- tagged-h addressing ----
    const int prow = (w - 4) * 4 + hi;   // h-waves: probed/staged row 0..15
    const unsigned long long tb0 = (unsigned long long)thbuf0;
    const unsigned long long tb1 = (unsigned long long)thbuf1;
    const unsigned long long poff =
        ((unsigned long long)(g * 16 + (isx ? 0 : prow)) * 256) * 8 + (unsigned)(r0 * 16);
    const unsigned long long soff =
        ((unsigned long long)(g * 16 + pr2) * 256 + wgi * 16 + (ht & 15)) * 8;
    unsigned long long pubword = 0ull;   // publish word: LIVE across iterations

    // ---- swizzle constants ----
    const int xorv = (r0 & 7) << 4;      // frag-read XOR (row = r0)

    // ---- x prefetch regs (x-waves): 8 float4 = this wave-row's full 2KB ----
    float4 xr[8];
    const int xrow = w * 4 + hi;         // x-waves: staged row 0..15
    const int xwoff = SWZ(xrow, r0 * 8);

    // ---- prologue: stage x_0 into xlds0, prefetch x_1 ----
    if (isx) {
        const float* xb = x + ((size_t)(g * 16 + xrow)) * ISZ + r0 * 4;
        #pragma unroll
        for (int s = 0; s < 8; ++s) xr[s] = *(const float4*)(xb + s * 64);
        #pragma unroll
        for (int s = 0; s < 8; ++s) {
            float4 v = xr[s];
            ushort4 o;
            o.x = f2bf(v.x); o.y = f2bf(v.y); o.z = f2bf(v.z); o.w = f2bf(v.w);
            *(ushort4*)(xlds0 + xrow * XH + xwoff + s * 128) = o;
        }
        const float* xb1 = x + ((size_t)BATCH + g * 16 + xrow) * ISZ + r0 * 4;
        #pragma unroll
        for (int s = 0; s < 8; ++s) xr[s] = *(const float4*)(xb1 + s * 64);
    }
    __syncthreads();

    #pragma unroll 1
    for (int t = 0; ; ++t) {
        // ================= phase 1 =================
        if (isx) {
            if (t < T_STEPS) {
                // -- x-MFMA from xlds[t&1]: gates_x, K in [0,512) --
                f32x4 a0a = {0.f,0.f,0.f,0.f}, a0b = {0.f,0.f,0.f,0.f};
                f32x4 a1a = {0.f,0.f,0.f,0.f}, a1b = {0.f,0.f,0.f,0.f};
                const char* xsrc = ((t & 1) ? xlds1 : xlds0) + r0 * XH;
                #pragma unroll
                for (int it = 0; it < 16; it += 2) {
                    bf16x8 ae = *(const bf16x8*)(xsrc + ((hi * 16 + it * 64) ^ xorv));
                    bf16x8 ao = *(const bf16x8*)(xsrc + ((hi * 16 + (it + 1) * 64) ^ xorv));
                    a0a = __builtin_amdgcn_mfma_f32_16x16x32_bf16(ae, wf0[it],   a0a, 0, 0, 0);
                    a1a = __builtin_amdgcn_mfma_f32_16x16x32_bf16(ae, wf1[it],   a1a, 0, 0, 0);
                    a0b = __builtin_amdgcn_mfma_f32_16x16x32_bf16(ao, wf0[it+1], a0b, 0, 0, 0);
                    a1b = __builtin_amdgcn_mfma_f32_16x16x32_bf16(ao, wf1[it+1], a1b, 0, 0, 0);
                }
                #pragma unroll
                for (int j = 0; j < 4; ++j) {
                    gbuf[gate][hi * 4 + j][r0]      = a0a[j] + a0b[j] + bv0;
                    gbuf[gate][hi * 4 + j][16 + r0] = a1a[j] + a1b[j] + bv1;
                }
                // -- stage x_{t+1}, prefetch x_{t+2} --
                if (t + 1 < T_STEPS) {
                    char* xd = (((t + 1) & 1) ? xlds1 : xlds0) + xrow * XH + xwoff;
                    #pragma unroll
                    for (int s = 0; s < 8; ++s) {
                        float4 v = xr[s];
                        ushort4 o;
                        o.x = f2bf(v.x); o.y = f2bf(v.y); o.z = f2bf(v.z); o.w = f2bf(v.w);
                        *(ushort4*)(xd + s * 128) = o;
                    }
                    int tp = (t + 2 < T_STEPS) ? t + 2 : T_STEPS - 1;
                    const float* xb = x + ((size_t)tp * BATCH + g * 16 + xrow) * ISZ + r0 * 4;
                    #pragma unroll
                    for (int s = 0; s < 8; ++s) xr[s] = *(const float4*)(xb + s * 64);
                }
            }
        } else {
            char* hd = hlds + prow * XH + (SWZ(prow, r0 * 8));
            if (t == 0) {
                #pragma unroll
                for (int s = 0; s < 8; ++s)
                    *(unsigned long long*)(hd + s * 128) = 0ull;
            } else {
                // -- probe h_{t-1}: SELF-CONTAINED asm {8 loads + vmcnt(0)}.
                //    vmcnt(0) also drains our own publish store from step t-1
                //    (fused publish-ack + probe RTT: ONE round trip).
                const unsigned long long psrc = (((t - 1) & 1) ? tb1 : tb0) + poff;
                const int tgt = t;
                i32x4 q0, q1, q2, q3, q4, q5, q6, q7;
                while (true) {
                    asm volatile(
                        "global_load_dwordx4 %0, %8, off sc0 sc1\n\t"
                        "global_load_dwordx4 %1, %8, off offset:256 sc0 sc1\n\t"
                        "global_load_dwordx4 %2, %8, off offset:512 sc0 sc1\n\t"
                        "global_load_dwordx4 %3, %8, off offset:768 sc0 sc1\n\t"
                        "global_load_dwordx4 %4, %8, off offset:1024 sc0 sc1\n\t"
                        "global_load_dwordx4 %5, %8, off offset:1280 sc0 sc1\n\t"
                        "global_load_dwordx4 %6, %8, off offset:1536 sc0 sc1\n\t"
                        "global_load_dwordx4 %7, %8, off offset:1792 sc0 sc1\n\t"
                        "s_waitcnt vmcnt(0)"
                        : "=&v"(q0), "=&v"(q1), "=&v"(q2), "=&v"(q3),
                          "=&v"(q4), "=&v"(q5), "=&v"(q6), "=&v"(q7)
                        : "v"(psrc) : "memory");
                    bool ok = (q0[1] >= tgt) & (q0[3] >= tgt) & (q1[1] >= tgt) & (q1[3] >= tgt)
                            & (q2[1] >= tgt) & (q2[3] >= tgt) & (q3[1] >= tgt) & (q3[3] >= tgt)
                            & (q4[1] >= tgt) & (q4[3] >= tgt) & (q5[1] >= tgt) & (q5[3] >= tgt)
                            & (q6[1] >= tgt) & (q6[3] >= tgt) & (q7[1] >= tgt) & (q7[3] >= tgt);
                    if (__all((int)ok)) {
                        *(unsigned long long*)(hd +   0) = (unsigned long long)(unsigned)q0[0] | ((unsigned long long)(unsigned)q0[2] << 32);
                        *(unsigned long long*)(hd + 128) = (unsigned long long)(unsigned)q1[0] | ((unsigned long long)(unsigned)q1[2] << 32);
                        *(unsigned long long*)(hd + 256) = (unsigned long long)(unsigned)q2[0] | ((unsigned long long)(unsigned)q2[2] << 32);
                        *(unsigned long long*)(hd + 384) = (unsigned long long)(unsigned)q3[0] | ((unsigned long long)(unsigned)q3[2] << 32);
                        *(unsigned long long*)(hd + 512) = (unsigned long long)(unsigned)q4[0] | ((unsigned long long)(unsigned)q4[2] << 32);
                        *(unsigned long long*)(hd + 640) = (unsigned long long)(unsigned)q5[0] | ((unsigned long long)(unsigned)q5[2] << 32);
                        *(unsigned long long*)(hd + 768) = (unsigned long long)(unsigned)q6[0] | ((unsigned long long)(unsigned)q6[2] << 32);
                        *(unsigned long long*)(hd + 896) = (unsigned long long)(unsigned)q7[0] | ((unsigned long long)(unsigned)q7[2] << 32);
                        break;
                    }
                }
                // publish store from t-1 is now complete (vmcnt(0) above):
                // release pubword's register only here.
                asm volatile("" :: "v"(pubword));
            }
        }
        BARL();   // B2: hlds + gbuf(x half) ready (all cross-wave edges are LDS)

        // ================= phase 2 =================
        if (isx) {
            if (t > 0) {
                unsigned pw2 = *(const unsigned*)(hlds + wgi * XH + (SWZ(wgi, tid * 4)));
                float ps = woA * bf2f(pw2 & 0xffffu) + woB * bf2f(pw2 >> 16);
                ps += __shfl_xor(ps, 1);
                ps += __shfl_xor(ps, 2);
                ps += __shfl_xor(ps, 4);
                ps += __shfl_xor(ps, 8);
                ps += __shfl_xor(ps, 16);
                ps += __shfl_xor(ps, 32);
                if (lane == 0) obuf[w] = ps;
            }
        } else if (t < T_STEPS) {
            // -- h-MFMA from hlds: gates_h, K in [512,1024); RMW into gbuf --
            f32x4 a0a = {0.f,0.f,0.f,0.f}, a0b = {0.f,0.f,0.f,0.f};
            f32x4 a1a = {0.f,0.f,0.f,0.f}, a1b = {0.f,0.f,0.f,0.f};
            const char* hsrc = hlds + r0 * XH;
            #pragma unroll
            for (int it = 0; it < 16; it += 2) {
                bf16x8 ae = *(const bf16x8*)(hsrc + ((hi * 16 + it * 64) ^ xorv));
                bf16x8 ao = *(const bf16x8*)(hsrc + ((hi * 16 + (it + 1) * 64) ^ xorv));
                a0a = __builtin_amdgcn_mfma_f32_16x16x32_bf16(ae, wf0[it],   a0a, 0, 0, 0);
                a1a = __builtin_amdgcn_mfma_f32_16x16x32_bf16(ae, wf1[it],   a1a, 0, 0, 0);
                a0b = __builtin_amdgcn_mfma_f32_16x16x32_bf16(ao, wf0[it+1], a0b, 0, 0, 0);
                a1b = __builtin_amdgcn_mfma_f32_16x16x32_bf16(ao, wf1[it+1], a1b, 0, 0, 0);
            }
            #pragma unroll
            for (int j = 0; j < 4; ++j) {
                gbuf[gate][hi * 4 + j][r0]      += a0a[j] + a0b[j];
                gbuf[gate][hi * 4 + j][16 + r0] += a1a[j] + a1b[j];
            }
        }
        BARL();   // B3: gbuf complete, obuf ready

        if (t > 0 && tid == 0)
            out[(size_t)(t - 1) * BATCH + g * 16 + wgi] =
                obuf[0] + obuf[1] + obuf[2] + obuf[3] + bo;
        if (t == T_STEPS) break;

        // ================= phase 3 (h-waves only) =================
        if (!isx) {
            float iv0 = sigf(gbuf[0][pr2][cl]),     iv1 = sigf(gbuf[0][pr2][cl + 1]);
            float fv0 = sigf(gbuf[1][pr2][cl]),     fv1 = sigf(gbuf[1][pr2][cl + 1]);
            float gv0 = tanh_f(gbuf[2][pr2][cl]),   gv1 = tanh_f(gbuf[2][pr2][cl + 1]);
            float ov0 = sigf(gbuf[3][pr2][cl]),     ov1 = sigf(gbuf[3][pr2][cl + 1]);
            cst0 = fv0 * cst0 + iv0 * gv0;
            cst1 = fv1 * cst1 + iv1 * gv1;
            float h0f = ov0 * tanh_f(cst0);
            float h1f = ov1 * tanh_f(cst1);
            unsigned hv2 = (unsigned)f2bf(h0f) | ((unsigned)f2bf(h1f) << 16);
            pubword = (unsigned long long)hv2
                    | ((unsigned long long)(unsigned)(t + 1) << 32);
            unsigned long long dst = ((t & 1) ? tb1 : tb0) + soff;
            // Publish WITHOUT internal wait: the next probe's vmcnt(0) drains it.
            // pubword stays live until the dummy use after that probe.
            asm volatile("global_store_dwordx2 %0, %1, off sc0 sc1"
                         :: "v"(dst), "v"(pubword) : "memory");
        }
        BARL();   // B1: gbuf reads done before next step's writes
    }
}

// ---------------- host launcher ----------------
extern "C" void kernel_launch(void* const* d_in, const int* in_sizes, int n_in,
                              void* d_out, int out_size, void* d_ws, size_t ws_size,
                              hipStream_t stream) {
    const float* x    = (const float*)d_in[0];
    const float* Wih  = (const float*)d_in[1];
    const float* Whh  = (const float*)d_in[2];
    const float* bih  = (const float*)d_in[3];
    const float* bhh  = (const float*)d_in[4];
    const float* Wout = (const float*)d_in[5];
    const float* bout = (const float*)d_in[6];

    char* ws = (char*)d_ws;
    unsigned short*     Wcat = (unsigned short*)(ws);
    float*              bias = (float*)(ws + 4194304);
    unsigned long long* th0  = (unsigned long long*)(ws + 4202496);
    unsigned long long* th1  = (unsigned long long*)(ws + 4726784);
    float*              out  = (float*)d_out;

    pack_weights<<<2048, 256, 0, stream>>>(Wih, Whh, Wcat);
    init_state<<<2048, 256, 0, stream>>>((unsigned int*)th0, bias, bih, bhh);
    lstm_persist<<<256, 512, 0, stream>>>(x, Wcat, bias, Wout, bout, th0, th1, out);
}